// Round 2
// baseline (3028.691 us; speedup 1.0000x reference)
//
#include <hip/hip_runtime.h>
#include <hip/hip_bf16.h>

// ScalarBorn: 4th-order FD scalar wave + Born scattering with CPML, MI355X.
// R16 = R15 (XCD-banded, 2538us) + global-load hoisting: ALL LDS-independent
// global loads (y-stencil rows, prev, vb, zeta, psi_x/psi_y old) are issued at
// the TOP of step_fused, before barrier 1, so their L2 latency overlaps the
// LDS staging + barriers + x-phase compute instead of serializing after them.
// Both barriers kept (removal falsified R12/R13). Banding kept (R15, -33%).
// Falsified previously: aggregation (R8/R10), barrier removal (R12/R13),
// load cuts (R7), cooperative grid.sync (R4).

constexpr int NYX  = 400;
constexpr int NS   = 4;
constexpr int NREC = 100;
constexpr int NT   = 300;
constexpr int PAD  = 22;
constexpr int NP   = 444;
constexpr int NP2  = NP * NP;          // 197136
constexpr int SNP2 = NS * NP2;         // 788544
constexpr float DT    = 0.0005f;
constexpr float INVH  = 0.2f;
constexpr float INVH2 = 0.04f;
constexpr float C1A = 1.0f / 12.0f;
constexpr float C1B = 2.0f / 3.0f;
constexpr float C2A = -1.0f / 12.0f;
constexpr float C2B = 4.0f / 3.0f;
constexpr float C2C = -2.5f;

// interleaved state: element (b,s) pair for grid index idx lives at [2*idx, 2*idx+1]
__device__ __align__(16) float g_w[2][2 * SNP2];   // wavefield ping-pong
__device__ __align__(16) float g_px[2][2 * SNP2];  // psi_x dbuf
__device__ __align__(16) float g_py[2][2 * SNP2];  // psi_y dbuf
__device__ __align__(16) float g_zx[2 * SNP2];     // zeta_x
__device__ __align__(16) float g_zy[2 * SNP2];     // zeta_y
__device__ __align__(16) float g_vb[2 * NP2];      // (v2dt2, bscale) pairs
__device__ float g_pa[NP];
__device__ float g_pb[NP];
__device__ float g_fbg[NT * NS];
__device__ float g_fsc[NT * NS];
__device__ int   g_spos[2 * NS];
__device__ int   g_mode;               // 1 = bf16 io, 0 = f32 io

__device__ __forceinline__ int clampi(int v, int lo, int hi) {
    return v < lo ? lo : (v > hi ? hi : v);
}
__device__ __forceinline__ float in_ld(const void* p, int i) {
    if (g_mode) return __bfloat162float(((const __hip_bfloat16*)p)[i]);
    return ((const float*)p)[i];
}
__device__ __forceinline__ void out_st(void* p, int i, float v) {
    if (g_mode) ((__hip_bfloat16*)p)[i] = __float2bfloat16(v);
    else        ((float*)p)[i] = v;
}
// float4 = (b0,s0,b1,s1) at row yy, col pair (2i,2i+1) of shot s; 0 if row OOB
__device__ __forceinline__ float4 ld4(const float* w, int s, int yy, int i) {
    if ((unsigned)yy >= (unsigned)NP) return make_float4(0.f, 0.f, 0.f, 0.f);
    return *(const float4*)(w + 2 * (s * NP2 + yy * NP + 2 * i));
}

__global__ void detect_mode(const void* vptr) {
    if (threadIdx.x == 0 && blockIdx.x == 0) {
        const __hip_bfloat16* p = (const __hip_bfloat16*)vptr;
        int ok = 1;
        for (int i = 0; i < 32; i += 2) {
            float f = __bfloat162float(p[i]);
            if (!(f >= 1000.f && f <= 3000.f)) ok = 0;
        }
        g_mode = ok;
    }
}

__global__ void zero_state() {
    int i = blockIdx.x * blockDim.x + threadIdx.x;
    if (i >= SNP2 / 2) return;           // each array = 2*SNP2 floats = SNP2/2 float4
    float4 z = make_float4(0.f, 0.f, 0.f, 0.f);
    ((float4*)g_w[0])[i] = z;  ((float4*)g_w[1])[i] = z;
    ((float4*)g_px[0])[i] = z; ((float4*)g_px[1])[i] = z;
    ((float4*)g_py[0])[i] = z; ((float4*)g_py[1])[i] = z;
    ((float4*)g_zx)[i] = z;    ((float4*)g_zy)[i] = z;
}

__global__ void prep_pad(const void* __restrict__ v, const void* __restrict__ sc) {
    int i = blockIdx.x * blockDim.x + threadIdx.x;
    if (i >= NP2) return;
    int y = i / NP, x = i % NP;
    int vy = clampi(y - PAD, 0, NYX - 1);
    int vx = clampi(x - PAD, 0, NYX - 1);
    float vv = in_ld(v, vy * NYX + vx);
    float vd = vv * DT;
    float s = 0.f;
    if (y >= PAD && y < PAD + NYX && x >= PAD && x < PAD + NYX)
        s = in_ld(sc, (y - PAD) * NYX + (x - PAD));
    g_vb[2 * i]     = vd * vd;
    g_vb[2 * i + 1] = 2.f * vv * s * DT * DT;
    if (i < NP) {
        float fi = (float)i;
        float f1 = fminf(fmaxf((22.f - fi) * 0.05f, 0.f), 1.f);
        float f2 = fminf(fmaxf((fi - 421.f) * 0.05f, 0.f), 1.f);
        float frac = fmaxf(f1, f2);
        float sigma = 259.0408229f * frac * frac;
        const float alpha = 78.53981634f;
        float a = expf(-(sigma + alpha) * DT);
        g_pa[i] = a;
        g_pb[i] = (sigma > 0.f) ? sigma / (sigma + alpha) * (a - 1.f) : 0.f;
    }
}

__global__ void prep_src(const void* __restrict__ amp, const int* __restrict__ sloc,
                         const void* __restrict__ v, const void* __restrict__ sc) {
    int i = blockIdx.x * blockDim.x + threadIdx.x;
    if (i >= NT * NS) return;
    int s = i % NS, t = i / NS;
    int ly = clampi(sloc[s * 2 + 0], 0, NYX - 1);
    int lx = clampi(sloc[s * 2 + 1], 0, NYX - 1);
    float a  = in_ld(amp, s * NT + t);
    float vv = in_ld(v,  ly * NYX + lx);
    float ss = in_ld(sc, ly * NYX + lx);
    g_fbg[i] = -a * vv * vv * DT * DT;
    g_fsc[i] = -2.f * a * vv * ss * DT * DT;
    if (i < NS) {
        g_spos[2 * i]     = ly + PAD;
        g_spos[2 * i + 1] = lx + PAD;
    }
}

// one fused timestep. Block = row y of shot s; 256 threads x 2 points.
// 1-D grid of NS*NP=1776 blocks, XCD-banded: bid%8 = XCD, each XCD gets 222
// consecutive rows of one shot so the y-stencil stays in its local L2.
// All global loads issued up-front (none depend on LDS) so L2 latency
// overlaps the two barriers + x-phase instead of serializing after them.
// LDS layout: (b,s) pair of logical col c at float index 2*(c+2); pads zeroed.
__global__ void __launch_bounds__(256)
step_fused(int t, const int* __restrict__ rloc, const int* __restrict__ rbloc,
           void* __restrict__ out) {
    const int i = threadIdx.x;
    const int bid = blockIdx.x;
    const int s = (bid >> 1) & 3;                      // xcd = bid & 7; s = xcd>>1
    const int y = ((bid & 1) ? 222 : 0) + (bid >> 3);  // band-local row
    const int cur = t & 1, nxt = cur ^ 1;
    __shared__ __align__(16) float sw[904], spx[904];

    if (t > 0 && y == 0 && i < 2 * NREC) {    // record step t-1
        int r = i % NREC;
        bool isbg = i < NREC;
        const int* rl = isbg ? rbloc : rloc;
        int ry = clampi(rl[(s * NREC + r) * 2 + 0], 0, NYX - 1) + PAD;
        int rx = clampi(rl[(s * NREC + r) * 2 + 1], 0, NYX - 1) + PAD;
        float val = g_w[cur][2 * (s * NP2 + ry * NP + rx) + (isbg ? 0 : 1)];
        int base = isbg ? (2 * SNP2) : (2 * SNP2 + NS * NREC * NT);
        out_st(out, base + (s * NREC + r) * NT + (t - 1), val);
    }

    const bool active = i < 222;
    const int x0 = 2 * i, x1 = x0 + 1;
    const int yx  = y * NP + x0;
    const int idx = s * NP2 + yx;
    const bool pxreg  = (i <= 11 || i >= 210);
    const bool yframe = (y <= 23 || y >= 420);

    // ---------------- prefetch phase: issue every LDS-independent load ----
    const float4 z4 = make_float4(0.f, 0.f, 0.f, 0.f);
    float4 w4 = z4, prev = z4, vb = z4;
    float4 pxo = z4, zox = z4, zoy = z4;
    float4 m2 = z4, m1 = z4, p1 = z4, p2 = z4;      // interior y rows
    float4 wy[9];                                   // frame y rows
    float4 po[5];                                   // frame psi_y old
    float pbv5[5], pav5[5];
    float pbx0 = 0.f, pbx1 = 0.f, pax0 = 0.f, pax1 = 0.f;
    float pby = 0.f, pay = 0.f;

    if (active) {
        w4   = *(const float4*)(g_w[cur] + 2 * idx);
        vb   = *(const float4*)(g_vb + 2 * yx);
        prev = *(const float4*)(g_w[nxt] + 2 * idx);
        pby  = g_pb[y];
        pbx0 = g_pb[x0]; pbx1 = g_pb[x1];
        pax0 = g_pa[x0]; pax1 = g_pa[x1];
        if (pby != 0.f) {
            pay = g_pa[y];
            zoy = *(const float4*)(g_zy + 2 * idx);
        }
        if (pxreg && pbx0 != 0.f) {
            pxo = *(const float4*)(g_px[cur] + 2 * idx);
            zox = *(const float4*)(g_zx + 2 * idx);
        }
        if (yframe) {
            #pragma unroll
            for (int k = 0; k < 9; ++k)
                wy[k] = (k == 4) ? w4 : ld4(g_w[cur], s, y - 4 + k, i);
            #pragma unroll
            for (int k = 0; k < 5; ++k) {
                int yy = y - 2 + k;
                float pbv = ((unsigned)yy < (unsigned)NP) ? g_pb[yy] : 0.f;  // uniform
                pbv5[k] = pbv;
                pav5[k] = 0.f;
                po[k] = z4;
                if (pbv != 0.f) {
                    pav5[k] = g_pa[yy];
                    po[k] = *(const float4*)(g_py[cur] + 2 * (s * NP2 + yy * NP + x0));
                }
            }
        } else {
            m2 = *(const float4*)(g_w[cur] + 2 * (idx - 2 * NP));
            m1 = *(const float4*)(g_w[cur] + 2 * (idx - NP));
            p1 = *(const float4*)(g_w[cur] + 2 * (idx + NP));
            p2 = *(const float4*)(g_w[cur] + 2 * (idx + 2 * NP));
        }
        *(float4*)&sw[2 * x0 + 4] = w4;
    } else if (i == 222) {
        #pragma unroll
        for (int k = 0; k < 4; ++k) { sw[k] = 0.f; spx[k] = 0.f; }
    } else if (i == 223) {
        #pragma unroll
        for (int k = 892; k < 904; ++k) { sw[k] = 0.f; spx[k] = 0.f; }
    }
    __syncthreads();

    // ---- x stencils from LDS + own psi_x updates ----
    float d2x_b0 = 0.f, d2x_b1 = 0.f, d2x_s0 = 0.f, d2x_s1 = 0.f;
    float4 pxn = make_float4(0.f, 0.f, 0.f, 0.f);
    if (active) {
        float2 tm2 = *(const float2*)&sw[2 * (x0 - 2) + 4];
        float2 tm1 = *(const float2*)&sw[2 * (x0 - 1) + 4];
        float2 tp2 = *(const float2*)&sw[2 * (x0 + 2) + 4];
        float2 tp3 = *(const float2*)&sw[2 * (x0 + 3) + 4];
        d2x_b0 = (C2A * (tm2.x + tp2.x) + C2B * (tm1.x + w4.z) + C2C * w4.x) * INVH2;
        d2x_s0 = (C2A * (tm2.y + tp2.y) + C2B * (tm1.y + w4.w) + C2C * w4.y) * INVH2;
        d2x_b1 = (C2A * (tm1.x + tp3.x) + C2B * (w4.x + tp2.x) + C2C * w4.z) * INVH2;
        d2x_s1 = (C2A * (tm1.y + tp3.y) + C2B * (w4.y + tp2.y) + C2C * w4.w) * INVH2;
        if (pxreg && pbx0 != 0.f) {      // pb pair-uniform (frame edges even)
            float dwb0 = (C1A * tm2.x - C1B * tm1.x + C1B * w4.z - C1A * tp2.x) * INVH;
            float dws0 = (C1A * tm2.y - C1B * tm1.y + C1B * w4.w - C1A * tp2.y) * INVH;
            float dwb1 = (C1A * tm1.x - C1B * w4.x + C1B * tp2.x - C1A * tp3.x) * INVH;
            float dws1 = (C1A * tm1.y - C1B * w4.y + C1B * tp2.y - C1A * tp3.y) * INVH;
            pxn.x = pax0 * pxo.x + pbx0 * dwb0;
            pxn.y = pax0 * pxo.y + pbx0 * dws0;
            pxn.z = pax1 * pxo.z + pbx1 * dwb1;
            pxn.w = pax1 * pxo.w + pbx1 * dws1;
            *(float4*)(g_px[nxt] + 2 * idx) = pxn;
        }
        *(float4*)&spx[2 * x0 + 4] = pxn;
    }
    __syncthreads();
    if (!active) return;

    // ---- dpsi_x from LDS psi_x_new ----
    float dpx_b0 = 0.f, dpx_b1 = 0.f, dpx_s0 = 0.f, dpx_s1 = 0.f;
    if (pxreg) {
        float2 pm2 = *(const float2*)&spx[2 * (x0 - 2) + 4];
        float2 pm1 = *(const float2*)&spx[2 * (x0 - 1) + 4];
        float2 pp2 = *(const float2*)&spx[2 * (x0 + 2) + 4];
        float2 pp3 = *(const float2*)&spx[2 * (x0 + 3) + 4];
        dpx_b0 = (C1A * pm2.x - C1B * pm1.x + C1B * pxn.z - C1A * pp2.x) * INVH;
        dpx_s0 = (C1A * pm2.y - C1B * pm1.y + C1B * pxn.w - C1A * pp2.y) * INVH;
        dpx_b1 = (C1A * pm1.x - C1B * pxn.x + C1B * pp2.x - C1A * pp3.x) * INVH;
        dpx_s1 = (C1A * pm1.y - C1B * pxn.y + C1B * pp2.y - C1A * pp3.y) * INVH;
    }

    // ---- y direction (all inputs prefetched) ----
    float d2y_b0, d2y_b1, d2y_s0, d2y_s1;
    float dpy_b0 = 0.f, dpy_b1 = 0.f, dpy_s0 = 0.f, dpy_s1 = 0.f;
    if (yframe) {
        d2y_b0 = (C2A * (wy[2].x + wy[6].x) + C2B * (wy[3].x + wy[5].x) + C2C * wy[4].x) * INVH2;
        d2y_s0 = (C2A * (wy[2].y + wy[6].y) + C2B * (wy[3].y + wy[5].y) + C2C * wy[4].y) * INVH2;
        d2y_b1 = (C2A * (wy[2].z + wy[6].z) + C2B * (wy[3].z + wy[5].z) + C2C * wy[4].z) * INVH2;
        d2y_s1 = (C2A * (wy[2].w + wy[6].w) + C2B * (wy[3].w + wy[5].w) + C2C * wy[4].w) * INVH2;
        float4 pn[5];                        // psi_y_new rows y-2..y+2
        #pragma unroll
        for (int k = 0; k < 5; ++k) {
            float pbv = pbv5[k];
            float4 r = make_float4(0.f, 0.f, 0.f, 0.f);
            if (pbv != 0.f) {
                float pav = pav5[k];
                float db0 = (C1A * wy[k].x - C1B * wy[k+1].x + C1B * wy[k+3].x - C1A * wy[k+4].x) * INVH;
                float ds0 = (C1A * wy[k].y - C1B * wy[k+1].y + C1B * wy[k+3].y - C1A * wy[k+4].y) * INVH;
                float db1 = (C1A * wy[k].z - C1B * wy[k+1].z + C1B * wy[k+3].z - C1A * wy[k+4].z) * INVH;
                float ds1 = (C1A * wy[k].w - C1B * wy[k+1].w + C1B * wy[k+3].w - C1A * wy[k+4].w) * INVH;
                r.x = pav * po[k].x + pbv * db0;  r.y = pav * po[k].y + pbv * ds0;
                r.z = pav * po[k].z + pbv * db1;  r.w = pav * po[k].w + pbv * ds1;
            }
            pn[k] = r;
        }
        dpy_b0 = (C1A * pn[0].x - C1B * pn[1].x + C1B * pn[3].x - C1A * pn[4].x) * INVH;
        dpy_s0 = (C1A * pn[0].y - C1B * pn[1].y + C1B * pn[3].y - C1A * pn[4].y) * INVH;
        dpy_b1 = (C1A * pn[0].z - C1B * pn[1].z + C1B * pn[3].z - C1A * pn[4].z) * INVH;
        dpy_s1 = (C1A * pn[0].w - C1B * pn[1].w + C1B * pn[3].w - C1A * pn[4].w) * INVH;
        if (pby != 0.f)
            *(float4*)(g_py[nxt] + 2 * idx) = pn[2];
    } else {                                 // interior: rows prefetched
        d2y_b0 = (C2A * (m2.x + p2.x) + C2B * (m1.x + p1.x) + C2C * w4.x) * INVH2;
        d2y_s0 = (C2A * (m2.y + p2.y) + C2B * (m1.y + p1.y) + C2C * w4.y) * INVH2;
        d2y_b1 = (C2A * (m2.z + p2.z) + C2B * (m1.z + p1.z) + C2C * w4.z) * INVH2;
        d2y_s1 = (C2A * (m2.w + p2.w) + C2B * (m1.w + p1.w) + C2C * w4.w) * INVH2;
    }

    // ---- zeta (in-place, own points, paired float4; olds prefetched) ----
    float zy_b0 = 0.f, zy_b1 = 0.f, zy_s0 = 0.f, zy_s1 = 0.f;
    float zx_b0 = 0.f, zx_b1 = 0.f, zx_s0 = 0.f, zx_s1 = 0.f;
    if (pby != 0.f) {
        zy_b0 = pay * zoy.x + pby * (d2y_b0 + dpy_b0);
        zy_s0 = pay * zoy.y + pby * (d2y_s0 + dpy_s0);
        zy_b1 = pay * zoy.z + pby * (d2y_b1 + dpy_b1);
        zy_s1 = pay * zoy.w + pby * (d2y_s1 + dpy_s1);
        *(float4*)(g_zy + 2 * idx) = make_float4(zy_b0, zy_s0, zy_b1, zy_s1);
    }
    if (pbx0 != 0.f && pxreg) {              // pair-uniform
        zx_b0 = pax0 * zox.x + pbx0 * (d2x_b0 + dpx_b0);
        zx_s0 = pax0 * zox.y + pbx0 * (d2x_s0 + dpx_s0);
        zx_b1 = pax1 * zox.z + pbx1 * (d2x_b1 + dpx_b1);
        zx_s1 = pax1 * zox.w + pbx1 * (d2x_s1 + dpx_s1);
        *(float4*)(g_zx + 2 * idx) = make_float4(zx_b0, zx_s0, zx_b1, zx_s1);
    } else if (pbx0 != 0.f) {                // non-pxreg cols with pb!=0 don't exist
    }

    // ---- lap + leapfrog + Born + source ----
    float lap_b0 = d2y_b0 + d2x_b0 + dpy_b0 + dpx_b0 + zy_b0 + zx_b0;
    float lap_s0 = d2y_s0 + d2x_s0 + dpy_s0 + dpx_s0 + zy_s0 + zx_s0;
    float lap_b1 = d2y_b1 + d2x_b1 + dpy_b1 + dpx_b1 + zy_b1 + zx_b1;
    float lap_s1 = d2y_s1 + d2x_s1 + dpy_s1 + dpx_s1 + zy_s1 + zx_s1;
    float wn_b0 = vb.x * lap_b0 + 2.f * w4.x - prev.x;
    float wn_s0 = vb.x * lap_s0 + 2.f * w4.y - prev.y + vb.y * lap_b0;
    float wn_b1 = vb.z * lap_b1 + 2.f * w4.z - prev.z;
    float wn_s1 = vb.z * lap_s1 + 2.f * w4.w - prev.w + vb.w * lap_b1;
    if (y == g_spos[2 * s]) {
        int sx = g_spos[2 * s + 1];
        if (sx == x0)      { wn_b0 += g_fbg[t * NS + s]; wn_s0 += g_fsc[t * NS + s]; }
        else if (sx == x1) { wn_b1 += g_fbg[t * NS + s]; wn_s1 += g_fsc[t * NS + s]; }
    }
    *(float4*)(g_w[nxt] + 2 * idx) = make_float4(wn_b0, wn_s0, wn_b1, wn_s1);
}

__global__ void finalize(const int* __restrict__ rloc, const int* __restrict__ rbloc,
                         void* __restrict__ out) {
    int i = blockIdx.x * blockDim.x + threadIdx.x;
    const float* w0 = g_w[0];     // NT even: newest field in buffer 0
    if (i < SNP2) {
        out_st(out, i,        w0[2 * i]);       // bg flat
        out_st(out, SNP2 + i, w0[2 * i + 1]);   // scattered flat
    }
    if (i < 2 * NS * NREC) {      // record last step (t = NT-1)
        bool isbg = i < NS * NREC;
        int k = isbg ? i : i - NS * NREC;
        int s = k / NREC, r = k % NREC;
        const int* rl = isbg ? rbloc : rloc;
        int ry = clampi(rl[(s * NREC + r) * 2 + 0], 0, NYX - 1) + PAD;
        int rx = clampi(rl[(s * NREC + r) * 2 + 1], 0, NYX - 1) + PAD;
        float val = w0[2 * (s * NP2 + ry * NP + rx) + (isbg ? 0 : 1)];
        int base = isbg ? (2 * SNP2) : (2 * SNP2 + NS * NREC * NT);
        out_st(out, base + (s * NREC + r) * NT + (NT - 1), val);
    }
}

extern "C" void kernel_launch(void* const* d_in, const int* in_sizes, int n_in,
                              void* d_out, int out_size, void* d_ws, size_t ws_size,
                              hipStream_t stream) {
    const void* v   = d_in[0];
    const void* sc  = d_in[1];
    const void* amp = d_in[2];
    const int* sloc  = (const int*)d_in[3];
    const int* rloc  = (const int*)d_in[4];
    const int* rbloc = (const int*)d_in[5];

    detect_mode<<<1, 64, 0, stream>>>(v);
    zero_state<<<(SNP2 / 2 + 255) / 256, 256, 0, stream>>>();
    prep_pad<<<(NP2 + 255) / 256, 256, 0, stream>>>(v, sc);
    prep_src<<<(NT * NS + 255) / 256, 256, 0, stream>>>(amp, sloc, v, sc);

    for (int t = 0; t < NT; ++t)
        step_fused<<<NS * NP, 256, 0, stream>>>(t, rloc, rbloc, d_out);

    finalize<<<(SNP2 + 255) / 256, 256, 0, stream>>>(rloc, rbloc, d_out);
}

// Round 3
// 2658.618 us; speedup vs baseline: 1.1392x; 1.1392x over previous
//
#include <hip/hip_runtime.h>
#include <hip/hip_bf16.h>

// ScalarBorn: 4th-order FD scalar wave + Born scattering with CPML, MI355X.
// R17 = R15 (XCD-banded, 2538us) + REGISTER-CHEAP hoist: only prev, vb and the
// 4 interior y-rows (m2,m1,p1,p2) prefetch before barrier 1 (+24 VGPRs on the
// interior path, below the frame path's existing peak liveness -> occupancy
// preserved). R16's full hoist (frame wy[9]/po[5] too) blew VGPR max-over-paths
// and regressed +19% -- occupancy/TLP is the binding resource here.
// Falsified: full hoist (R16), aggregation (R8/R10), barrier removal (R12/R13),
// load cuts (R7), cooperative grid.sync (R4).

constexpr int NYX  = 400;
constexpr int NS   = 4;
constexpr int NREC = 100;
constexpr int NT   = 300;
constexpr int PAD  = 22;
constexpr int NP   = 444;
constexpr int NP2  = NP * NP;          // 197136
constexpr int SNP2 = NS * NP2;         // 788544
constexpr float DT    = 0.0005f;
constexpr float INVH  = 0.2f;
constexpr float INVH2 = 0.04f;
constexpr float C1A = 1.0f / 12.0f;
constexpr float C1B = 2.0f / 3.0f;
constexpr float C2A = -1.0f / 12.0f;
constexpr float C2B = 4.0f / 3.0f;
constexpr float C2C = -2.5f;

// interleaved state: element (b,s) pair for grid index idx lives at [2*idx, 2*idx+1]
__device__ __align__(16) float g_w[2][2 * SNP2];   // wavefield ping-pong
__device__ __align__(16) float g_px[2][2 * SNP2];  // psi_x dbuf
__device__ __align__(16) float g_py[2][2 * SNP2];  // psi_y dbuf
__device__ __align__(16) float g_zx[2 * SNP2];     // zeta_x
__device__ __align__(16) float g_zy[2 * SNP2];     // zeta_y
__device__ __align__(16) float g_vb[2 * NP2];      // (v2dt2, bscale) pairs
__device__ float g_pa[NP];
__device__ float g_pb[NP];
__device__ float g_fbg[NT * NS];
__device__ float g_fsc[NT * NS];
__device__ int   g_spos[2 * NS];
__device__ int   g_mode;               // 1 = bf16 io, 0 = f32 io

__device__ __forceinline__ int clampi(int v, int lo, int hi) {
    return v < lo ? lo : (v > hi ? hi : v);
}
__device__ __forceinline__ float in_ld(const void* p, int i) {
    if (g_mode) return __bfloat162float(((const __hip_bfloat16*)p)[i]);
    return ((const float*)p)[i];
}
__device__ __forceinline__ void out_st(void* p, int i, float v) {
    if (g_mode) ((__hip_bfloat16*)p)[i] = __float2bfloat16(v);
    else        ((float*)p)[i] = v;
}
// float4 = (b0,s0,b1,s1) at row yy, col pair (2i,2i+1) of shot s; 0 if row OOB
__device__ __forceinline__ float4 ld4(const float* w, int s, int yy, int i) {
    if ((unsigned)yy >= (unsigned)NP) return make_float4(0.f, 0.f, 0.f, 0.f);
    return *(const float4*)(w + 2 * (s * NP2 + yy * NP + 2 * i));
}

__global__ void detect_mode(const void* vptr) {
    if (threadIdx.x == 0 && blockIdx.x == 0) {
        const __hip_bfloat16* p = (const __hip_bfloat16*)vptr;
        int ok = 1;
        for (int i = 0; i < 32; i += 2) {
            float f = __bfloat162float(p[i]);
            if (!(f >= 1000.f && f <= 3000.f)) ok = 0;
        }
        g_mode = ok;
    }
}

__global__ void zero_state() {
    int i = blockIdx.x * blockDim.x + threadIdx.x;
    if (i >= SNP2 / 2) return;           // each array = 2*SNP2 floats = SNP2/2 float4
    float4 z = make_float4(0.f, 0.f, 0.f, 0.f);
    ((float4*)g_w[0])[i] = z;  ((float4*)g_w[1])[i] = z;
    ((float4*)g_px[0])[i] = z; ((float4*)g_px[1])[i] = z;
    ((float4*)g_py[0])[i] = z; ((float4*)g_py[1])[i] = z;
    ((float4*)g_zx)[i] = z;    ((float4*)g_zy)[i] = z;
}

__global__ void prep_pad(const void* __restrict__ v, const void* __restrict__ sc) {
    int i = blockIdx.x * blockDim.x + threadIdx.x;
    if (i >= NP2) return;
    int y = i / NP, x = i % NP;
    int vy = clampi(y - PAD, 0, NYX - 1);
    int vx = clampi(x - PAD, 0, NYX - 1);
    float vv = in_ld(v, vy * NYX + vx);
    float vd = vv * DT;
    float s = 0.f;
    if (y >= PAD && y < PAD + NYX && x >= PAD && x < PAD + NYX)
        s = in_ld(sc, (y - PAD) * NYX + (x - PAD));
    g_vb[2 * i]     = vd * vd;
    g_vb[2 * i + 1] = 2.f * vv * s * DT * DT;
    if (i < NP) {
        float fi = (float)i;
        float f1 = fminf(fmaxf((22.f - fi) * 0.05f, 0.f), 1.f);
        float f2 = fminf(fmaxf((fi - 421.f) * 0.05f, 0.f), 1.f);
        float frac = fmaxf(f1, f2);
        float sigma = 259.0408229f * frac * frac;
        const float alpha = 78.53981634f;
        float a = expf(-(sigma + alpha) * DT);
        g_pa[i] = a;
        g_pb[i] = (sigma > 0.f) ? sigma / (sigma + alpha) * (a - 1.f) : 0.f;
    }
}

__global__ void prep_src(const void* __restrict__ amp, const int* __restrict__ sloc,
                         const void* __restrict__ v, const void* __restrict__ sc) {
    int i = blockIdx.x * blockDim.x + threadIdx.x;
    if (i >= NT * NS) return;
    int s = i % NS, t = i / NS;
    int ly = clampi(sloc[s * 2 + 0], 0, NYX - 1);
    int lx = clampi(sloc[s * 2 + 1], 0, NYX - 1);
    float a  = in_ld(amp, s * NT + t);
    float vv = in_ld(v,  ly * NYX + lx);
    float ss = in_ld(sc, ly * NYX + lx);
    g_fbg[i] = -a * vv * vv * DT * DT;
    g_fsc[i] = -2.f * a * vv * ss * DT * DT;
    if (i < NS) {
        g_spos[2 * i]     = ly + PAD;
        g_spos[2 * i + 1] = lx + PAD;
    }
}

// one fused timestep. Block = row y of shot s; 256 threads x 2 points.
// 1-D grid of NS*NP=1776 blocks, XCD-banded: bid%8 = XCD, each XCD gets 222
// consecutive rows of one shot so the y-stencil stays in its local L2.
// LDS layout: (b,s) pair of logical col c at float index 2*(c+2); pads zeroed.
__global__ void __launch_bounds__(256)
step_fused(int t, const int* __restrict__ rloc, const int* __restrict__ rbloc,
           void* __restrict__ out) {
    const int i = threadIdx.x;
    const int bid = blockIdx.x;
    const int s = (bid >> 1) & 3;                      // xcd = bid & 7; s = xcd>>1
    const int y = ((bid & 1) ? 222 : 0) + (bid >> 3);  // band-local row
    const int cur = t & 1, nxt = cur ^ 1;
    __shared__ __align__(16) float sw[904], spx[904];

    if (t > 0 && y == 0 && i < 2 * NREC) {    // record step t-1
        int r = i % NREC;
        bool isbg = i < NREC;
        const int* rl = isbg ? rbloc : rloc;
        int ry = clampi(rl[(s * NREC + r) * 2 + 0], 0, NYX - 1) + PAD;
        int rx = clampi(rl[(s * NREC + r) * 2 + 1], 0, NYX - 1) + PAD;
        float val = g_w[cur][2 * (s * NP2 + ry * NP + rx) + (isbg ? 0 : 1)];
        int base = isbg ? (2 * SNP2) : (2 * SNP2 + NS * NREC * NT);
        out_st(out, base + (s * NREC + r) * NT + (t - 1), val);
    }

    const bool active = i < 222;
    const int x0 = 2 * i, x1 = x0 + 1;
    const int yx  = y * NP + x0;
    const int idx = s * NP2 + yx;
    const bool yframe = (y <= 23 || y >= 420);

    // ---- register-cheap prefetch: common-path loads only ----
    const float4 z4 = make_float4(0.f, 0.f, 0.f, 0.f);
    float4 w4 = z4, prev = z4, vb = z4;
    float4 m2 = z4, m1 = z4, p1 = z4, p2 = z4;      // interior y rows
    if (active) {
        w4   = *(const float4*)(g_w[cur] + 2 * idx);
        prev = *(const float4*)(g_w[nxt] + 2 * idx);
        vb   = *(const float4*)(g_vb + 2 * yx);
        if (!yframe) {
            m2 = *(const float4*)(g_w[cur] + 2 * (idx - 2 * NP));
            m1 = *(const float4*)(g_w[cur] + 2 * (idx - NP));
            p1 = *(const float4*)(g_w[cur] + 2 * (idx + NP));
            p2 = *(const float4*)(g_w[cur] + 2 * (idx + 2 * NP));
        }
        *(float4*)&sw[2 * x0 + 4] = w4;
    } else if (i == 222) {
        #pragma unroll
        for (int k = 0; k < 4; ++k) { sw[k] = 0.f; spx[k] = 0.f; }
    } else if (i == 223) {
        #pragma unroll
        for (int k = 892; k < 904; ++k) { sw[k] = 0.f; spx[k] = 0.f; }
    }
    __syncthreads();

    // ---- x stencils from LDS + own psi_x updates ----
    const bool pxreg = (i <= 11 || i >= 210);
    float pbx0 = 0.f, pbx1 = 0.f, pax0 = 0.f, pax1 = 0.f;
    float d2x_b0 = 0.f, d2x_b1 = 0.f, d2x_s0 = 0.f, d2x_s1 = 0.f;
    float4 pxn = make_float4(0.f, 0.f, 0.f, 0.f);
    float2 tm2, tm1, tp2, tp3;
    if (active) {
        tm2 = *(const float2*)&sw[2 * (x0 - 2) + 4];
        tm1 = *(const float2*)&sw[2 * (x0 - 1) + 4];
        tp2 = *(const float2*)&sw[2 * (x0 + 2) + 4];
        tp3 = *(const float2*)&sw[2 * (x0 + 3) + 4];
        d2x_b0 = (C2A * (tm2.x + tp2.x) + C2B * (tm1.x + w4.z) + C2C * w4.x) * INVH2;
        d2x_s0 = (C2A * (tm2.y + tp2.y) + C2B * (tm1.y + w4.w) + C2C * w4.y) * INVH2;
        d2x_b1 = (C2A * (tm1.x + tp3.x) + C2B * (w4.x + tp2.x) + C2C * w4.z) * INVH2;
        d2x_s1 = (C2A * (tm1.y + tp3.y) + C2B * (w4.y + tp2.y) + C2C * w4.w) * INVH2;
        pbx0 = g_pb[x0]; pbx1 = g_pb[x1];
        pax0 = g_pa[x0]; pax1 = g_pa[x1];
        if (pxreg && pbx0 != 0.f) {      // pb pair-uniform (frame edges even)
            float4 pxo = *(const float4*)(g_px[cur] + 2 * idx);
            float dwb0 = (C1A * tm2.x - C1B * tm1.x + C1B * w4.z - C1A * tp2.x) * INVH;
            float dws0 = (C1A * tm2.y - C1B * tm1.y + C1B * w4.w - C1A * tp2.y) * INVH;
            float dwb1 = (C1A * tm1.x - C1B * w4.x + C1B * tp2.x - C1A * tp3.x) * INVH;
            float dws1 = (C1A * tm1.y - C1B * w4.y + C1B * tp2.y - C1A * tp3.y) * INVH;
            pxn.x = pax0 * pxo.x + pbx0 * dwb0;
            pxn.y = pax0 * pxo.y + pbx0 * dws0;
            pxn.z = pax1 * pxo.z + pbx1 * dwb1;
            pxn.w = pax1 * pxo.w + pbx1 * dws1;
            *(float4*)(g_px[nxt] + 2 * idx) = pxn;
        }
        *(float4*)&spx[2 * x0 + 4] = pxn;
    }
    __syncthreads();
    if (!active) return;

    // ---- dpsi_x from LDS psi_x_new ----
    float dpx_b0 = 0.f, dpx_b1 = 0.f, dpx_s0 = 0.f, dpx_s1 = 0.f;
    if (pxreg) {
        float2 pm2 = *(const float2*)&spx[2 * (x0 - 2) + 4];
        float2 pm1 = *(const float2*)&spx[2 * (x0 - 1) + 4];
        float2 pp2 = *(const float2*)&spx[2 * (x0 + 2) + 4];
        float2 pp3 = *(const float2*)&spx[2 * (x0 + 3) + 4];
        dpx_b0 = (C1A * pm2.x - C1B * pm1.x + C1B * pxn.z - C1A * pp2.x) * INVH;
        dpx_s0 = (C1A * pm2.y - C1B * pm1.y + C1B * pxn.w - C1A * pp2.y) * INVH;
        dpx_b1 = (C1A * pm1.x - C1B * pxn.x + C1B * pp2.x - C1A * pp3.x) * INVH;
        dpx_s1 = (C1A * pm1.y - C1B * pxn.y + C1B * pp2.y - C1A * pp3.y) * INVH;
    }

    // ---- y direction ----
    const float pby = g_pb[y];               // block-uniform
    float d2y_b0, d2y_b1, d2y_s0, d2y_s1;
    float dpy_b0 = 0.f, dpy_b1 = 0.f, dpy_s0 = 0.f, dpy_s1 = 0.f;
    if (yframe) {
        float4 wy[9];                        // rows y-4..y+4, (b0,s0,b1,s1)
        #pragma unroll
        for (int k = 0; k < 9; ++k)
            wy[k] = (k == 4) ? w4 : ld4(g_w[cur], s, y - 4 + k, i);
        d2y_b0 = (C2A * (wy[2].x + wy[6].x) + C2B * (wy[3].x + wy[5].x) + C2C * wy[4].x) * INVH2;
        d2y_s0 = (C2A * (wy[2].y + wy[6].y) + C2B * (wy[3].y + wy[5].y) + C2C * wy[4].y) * INVH2;
        d2y_b1 = (C2A * (wy[2].z + wy[6].z) + C2B * (wy[3].z + wy[5].z) + C2C * wy[4].z) * INVH2;
        d2y_s1 = (C2A * (wy[2].w + wy[6].w) + C2B * (wy[3].w + wy[5].w) + C2C * wy[4].w) * INVH2;
        float4 pn[5];                        // psi_y_new rows y-2..y+2
        #pragma unroll
        for (int k = 0; k < 5; ++k) {
            int yy = y - 2 + k;
            float pbv = ((unsigned)yy < (unsigned)NP) ? g_pb[yy] : 0.f;  // uniform
            float4 r = make_float4(0.f, 0.f, 0.f, 0.f);
            if (pbv != 0.f) {
                float pav = g_pa[yy];
                float4 po = *(const float4*)(g_py[cur] + 2 * (s * NP2 + yy * NP + x0));
                float db0 = (C1A * wy[k].x - C1B * wy[k+1].x + C1B * wy[k+3].x - C1A * wy[k+4].x) * INVH;
                float ds0 = (C1A * wy[k].y - C1B * wy[k+1].y + C1B * wy[k+3].y - C1A * wy[k+4].y) * INVH;
                float db1 = (C1A * wy[k].z - C1B * wy[k+1].z + C1B * wy[k+3].z - C1A * wy[k+4].z) * INVH;
                float ds1 = (C1A * wy[k].w - C1B * wy[k+1].w + C1B * wy[k+3].w - C1A * wy[k+4].w) * INVH;
                r.x = pav * po.x + pbv * db0;  r.y = pav * po.y + pbv * ds0;
                r.z = pav * po.z + pbv * db1;  r.w = pav * po.w + pbv * ds1;
            }
            pn[k] = r;
        }
        dpy_b0 = (C1A * pn[0].x - C1B * pn[1].x + C1B * pn[3].x - C1A * pn[4].x) * INVH;
        dpy_s0 = (C1A * pn[0].y - C1B * pn[1].y + C1B * pn[3].y - C1A * pn[4].y) * INVH;
        dpy_b1 = (C1A * pn[0].z - C1B * pn[1].z + C1B * pn[3].z - C1A * pn[4].z) * INVH;
        dpy_s1 = (C1A * pn[0].w - C1B * pn[1].w + C1B * pn[3].w - C1A * pn[4].w) * INVH;
        if (pby != 0.f)
            *(float4*)(g_py[nxt] + 2 * idx) = pn[2];
    } else {                                 // interior: rows prefetched pre-barrier
        d2y_b0 = (C2A * (m2.x + p2.x) + C2B * (m1.x + p1.x) + C2C * w4.x) * INVH2;
        d2y_s0 = (C2A * (m2.y + p2.y) + C2B * (m1.y + p1.y) + C2C * w4.y) * INVH2;
        d2y_b1 = (C2A * (m2.z + p2.z) + C2B * (m1.z + p1.z) + C2C * w4.z) * INVH2;
        d2y_s1 = (C2A * (m2.w + p2.w) + C2B * (m1.w + p1.w) + C2C * w4.w) * INVH2;
    }

    // ---- zeta (in-place, own points, paired float4) ----
    float zy_b0 = 0.f, zy_b1 = 0.f, zy_s0 = 0.f, zy_s1 = 0.f;
    float zx_b0 = 0.f, zx_b1 = 0.f, zx_s0 = 0.f, zx_s1 = 0.f;
    if (pby != 0.f) {
        float pay = g_pa[y];
        float4 zo = *(const float4*)(g_zy + 2 * idx);
        zy_b0 = pay * zo.x + pby * (d2y_b0 + dpy_b0);
        zy_s0 = pay * zo.y + pby * (d2y_s0 + dpy_s0);
        zy_b1 = pay * zo.z + pby * (d2y_b1 + dpy_b1);
        zy_s1 = pay * zo.w + pby * (d2y_s1 + dpy_s1);
        *(float4*)(g_zy + 2 * idx) = make_float4(zy_b0, zy_s0, zy_b1, zy_s1);
    }
    if (pbx0 != 0.f) {                       // pair-uniform
        float4 zo = *(const float4*)(g_zx + 2 * idx);
        zx_b0 = pax0 * zo.x + pbx0 * (d2x_b0 + dpx_b0);
        zx_s0 = pax0 * zo.y + pbx0 * (d2x_s0 + dpx_s0);
        zx_b1 = pax1 * zo.z + pbx1 * (d2x_b1 + dpx_b1);
        zx_s1 = pax1 * zo.w + pbx1 * (d2x_s1 + dpx_s1);
        *(float4*)(g_zx + 2 * idx) = make_float4(zx_b0, zx_s0, zx_b1, zx_s1);
    }

    // ---- lap + leapfrog + Born + source (vb, prev prefetched) ----
    float lap_b0 = d2y_b0 + d2x_b0 + dpy_b0 + dpx_b0 + zy_b0 + zx_b0;
    float lap_s0 = d2y_s0 + d2x_s0 + dpy_s0 + dpx_s0 + zy_s0 + zx_s0;
    float lap_b1 = d2y_b1 + d2x_b1 + dpy_b1 + dpx_b1 + zy_b1 + zx_b1;
    float lap_s1 = d2y_s1 + d2x_s1 + dpy_s1 + dpx_s1 + zy_s1 + zx_s1;
    float wn_b0 = vb.x * lap_b0 + 2.f * w4.x - prev.x;
    float wn_s0 = vb.x * lap_s0 + 2.f * w4.y - prev.y + vb.y * lap_b0;
    float wn_b1 = vb.z * lap_b1 + 2.f * w4.z - prev.z;
    float wn_s1 = vb.z * lap_s1 + 2.f * w4.w - prev.w + vb.w * lap_b1;
    if (y == g_spos[2 * s]) {
        int sx = g_spos[2 * s + 1];
        if (sx == x0)      { wn_b0 += g_fbg[t * NS + s]; wn_s0 += g_fsc[t * NS + s]; }
        else if (sx == x1) { wn_b1 += g_fbg[t * NS + s]; wn_s1 += g_fsc[t * NS + s]; }
    }
    *(float4*)(g_w[nxt] + 2 * idx) = make_float4(wn_b0, wn_s0, wn_b1, wn_s1);
}

__global__ void finalize(const int* __restrict__ rloc, const int* __restrict__ rbloc,
                         void* __restrict__ out) {
    int i = blockIdx.x * blockDim.x + threadIdx.x;
    const float* w0 = g_w[0];     // NT even: newest field in buffer 0
    if (i < SNP2) {
        out_st(out, i,        w0[2 * i]);       // bg flat
        out_st(out, SNP2 + i, w0[2 * i + 1]);   // scattered flat
    }
    if (i < 2 * NS * NREC) {      // record last step (t = NT-1)
        bool isbg = i < NS * NREC;
        int k = isbg ? i : i - NS * NREC;
        int s = k / NREC, r = k % NREC;
        const int* rl = isbg ? rbloc : rloc;
        int ry = clampi(rl[(s * NREC + r) * 2 + 0], 0, NYX - 1) + PAD;
        int rx = clampi(rl[(s * NREC + r) * 2 + 1], 0, NYX - 1) + PAD;
        float val = w0[2 * (s * NP2 + ry * NP + rx) + (isbg ? 0 : 1)];
        int base = isbg ? (2 * SNP2) : (2 * SNP2 + NS * NREC * NT);
        out_st(out, base + (s * NREC + r) * NT + (NT - 1), val);
    }
}

extern "C" void kernel_launch(void* const* d_in, const int* in_sizes, int n_in,
                              void* d_out, int out_size, void* d_ws, size_t ws_size,
                              hipStream_t stream) {
    const void* v   = d_in[0];
    const void* sc  = d_in[1];
    const void* amp = d_in[2];
    const int* sloc  = (const int*)d_in[3];
    const int* rloc  = (const int*)d_in[4];
    const int* rbloc = (const int*)d_in[5];

    detect_mode<<<1, 64, 0, stream>>>(v);
    zero_state<<<(SNP2 / 2 + 255) / 256, 256, 0, stream>>>();
    prep_pad<<<(NP2 + 255) / 256, 256, 0, stream>>>(v, sc);
    prep_src<<<(NT * NS + 255) / 256, 256, 0, stream>>>(amp, sloc, v, sc);

    for (int t = 0; t < NT; ++t)
        step_fused<<<NS * NP, 256, 0, stream>>>(t, rloc, rbloc, d_out);

    finalize<<<(SNP2 + 255) / 256, 256, 0, stream>>>(rloc, rbloc, d_out);
}

// Round 4
// 2358.826 us; speedup vs baseline: 1.2840x; 1.1271x over previous
//
#include <hip/hip_runtime.h>
#include <hip/hip_bf16.h>

// ScalarBorn: 4th-order FD scalar wave + Born scattering with CPML, MI355X.
// R18 = R15 body EXACTLY (XCD-banded, session best 2538us) with
// __launch_bounds__(256, 7): forces VGPR <= 73 so 7 blocks/CU are resident
// and the 1776-block grid (6.94/CU) completes in ONE dispatch round instead
// of two. Theory: kernel is TLP-latency-bound; frame-path register fat
// (wy[9]+pn[5]) was capping residency at ~4-5 blocks/CU. Any spills land in
// the 11%-of-blocks frame branch.
// Falsified: full hoist (R16 +19%), cheap hoist (R17 +5%), aggregation
// (R8/R10), barrier removal (R12/R13), load cuts (R7), grid.sync (R4).

constexpr int NYX  = 400;
constexpr int NS   = 4;
constexpr int NREC = 100;
constexpr int NT   = 300;
constexpr int PAD  = 22;
constexpr int NP   = 444;
constexpr int NP2  = NP * NP;          // 197136
constexpr int SNP2 = NS * NP2;         // 788544
constexpr float DT    = 0.0005f;
constexpr float INVH  = 0.2f;
constexpr float INVH2 = 0.04f;
constexpr float C1A = 1.0f / 12.0f;
constexpr float C1B = 2.0f / 3.0f;
constexpr float C2A = -1.0f / 12.0f;
constexpr float C2B = 4.0f / 3.0f;
constexpr float C2C = -2.5f;

// interleaved state: element (b,s) pair for grid index idx lives at [2*idx, 2*idx+1]
__device__ __align__(16) float g_w[2][2 * SNP2];   // wavefield ping-pong
__device__ __align__(16) float g_px[2][2 * SNP2];  // psi_x dbuf
__device__ __align__(16) float g_py[2][2 * SNP2];  // psi_y dbuf
__device__ __align__(16) float g_zx[2 * SNP2];     // zeta_x
__device__ __align__(16) float g_zy[2 * SNP2];     // zeta_y
__device__ __align__(16) float g_vb[2 * NP2];      // (v2dt2, bscale) pairs
__device__ float g_pa[NP];
__device__ float g_pb[NP];
__device__ float g_fbg[NT * NS];
__device__ float g_fsc[NT * NS];
__device__ int   g_spos[2 * NS];
__device__ int   g_mode;               // 1 = bf16 io, 0 = f32 io

__device__ __forceinline__ int clampi(int v, int lo, int hi) {
    return v < lo ? lo : (v > hi ? hi : v);
}
__device__ __forceinline__ float in_ld(const void* p, int i) {
    if (g_mode) return __bfloat162float(((const __hip_bfloat16*)p)[i]);
    return ((const float*)p)[i];
}
__device__ __forceinline__ void out_st(void* p, int i, float v) {
    if (g_mode) ((__hip_bfloat16*)p)[i] = __float2bfloat16(v);
    else        ((float*)p)[i] = v;
}
// float4 = (b0,s0,b1,s1) at row yy, col pair (2i,2i+1) of shot s; 0 if row OOB
__device__ __forceinline__ float4 ld4(const float* w, int s, int yy, int i) {
    if ((unsigned)yy >= (unsigned)NP) return make_float4(0.f, 0.f, 0.f, 0.f);
    return *(const float4*)(w + 2 * (s * NP2 + yy * NP + 2 * i));
}

__global__ void detect_mode(const void* vptr) {
    if (threadIdx.x == 0 && blockIdx.x == 0) {
        const __hip_bfloat16* p = (const __hip_bfloat16*)vptr;
        int ok = 1;
        for (int i = 0; i < 32; i += 2) {
            float f = __bfloat162float(p[i]);
            if (!(f >= 1000.f && f <= 3000.f)) ok = 0;
        }
        g_mode = ok;
    }
}

__global__ void zero_state() {
    int i = blockIdx.x * blockDim.x + threadIdx.x;
    if (i >= SNP2 / 2) return;           // each array = 2*SNP2 floats = SNP2/2 float4
    float4 z = make_float4(0.f, 0.f, 0.f, 0.f);
    ((float4*)g_w[0])[i] = z;  ((float4*)g_w[1])[i] = z;
    ((float4*)g_px[0])[i] = z; ((float4*)g_px[1])[i] = z;
    ((float4*)g_py[0])[i] = z; ((float4*)g_py[1])[i] = z;
    ((float4*)g_zx)[i] = z;    ((float4*)g_zy)[i] = z;
}

__global__ void prep_pad(const void* __restrict__ v, const void* __restrict__ sc) {
    int i = blockIdx.x * blockDim.x + threadIdx.x;
    if (i >= NP2) return;
    int y = i / NP, x = i % NP;
    int vy = clampi(y - PAD, 0, NYX - 1);
    int vx = clampi(x - PAD, 0, NYX - 1);
    float vv = in_ld(v, vy * NYX + vx);
    float vd = vv * DT;
    float s = 0.f;
    if (y >= PAD && y < PAD + NYX && x >= PAD && x < PAD + NYX)
        s = in_ld(sc, (y - PAD) * NYX + (x - PAD));
    g_vb[2 * i]     = vd * vd;
    g_vb[2 * i + 1] = 2.f * vv * s * DT * DT;
    if (i < NP) {
        float fi = (float)i;
        float f1 = fminf(fmaxf((22.f - fi) * 0.05f, 0.f), 1.f);
        float f2 = fminf(fmaxf((fi - 421.f) * 0.05f, 0.f), 1.f);
        float frac = fmaxf(f1, f2);
        float sigma = 259.0408229f * frac * frac;
        const float alpha = 78.53981634f;
        float a = expf(-(sigma + alpha) * DT);
        g_pa[i] = a;
        g_pb[i] = (sigma > 0.f) ? sigma / (sigma + alpha) * (a - 1.f) : 0.f;
    }
}

__global__ void prep_src(const void* __restrict__ amp, const int* __restrict__ sloc,
                         const void* __restrict__ v, const void* __restrict__ sc) {
    int i = blockIdx.x * blockDim.x + threadIdx.x;
    if (i >= NT * NS) return;
    int s = i % NS, t = i / NS;
    int ly = clampi(sloc[s * 2 + 0], 0, NYX - 1);
    int lx = clampi(sloc[s * 2 + 1], 0, NYX - 1);
    float a  = in_ld(amp, s * NT + t);
    float vv = in_ld(v,  ly * NYX + lx);
    float ss = in_ld(sc, ly * NYX + lx);
    g_fbg[i] = -a * vv * vv * DT * DT;
    g_fsc[i] = -2.f * a * vv * ss * DT * DT;
    if (i < NS) {
        g_spos[2 * i]     = ly + PAD;
        g_spos[2 * i + 1] = lx + PAD;
    }
}

// one fused timestep. Block = row y of shot s; 256 threads x 2 points.
// 1-D grid of NS*NP=1776 blocks, XCD-banded: bid%8 = XCD, each XCD gets 222
// consecutive rows of one shot so the y-stencil stays in its local L2.
// __launch_bounds__(256,7): 7 blocks/CU resident -> whole grid in one round.
// LDS layout: (b,s) pair of logical col c at float index 2*(c+2); pads zeroed.
__global__ void __launch_bounds__(256, 7)
step_fused(int t, const int* __restrict__ rloc, const int* __restrict__ rbloc,
           void* __restrict__ out) {
    const int i = threadIdx.x;
    const int bid = blockIdx.x;
    const int s = (bid >> 1) & 3;                      // xcd = bid & 7; s = xcd>>1
    const int y = ((bid & 1) ? 222 : 0) + (bid >> 3);  // band-local row
    const int cur = t & 1, nxt = cur ^ 1;
    __shared__ __align__(16) float sw[904], spx[904];

    if (t > 0 && y == 0 && i < 2 * NREC) {    // record step t-1
        int r = i % NREC;
        bool isbg = i < NREC;
        const int* rl = isbg ? rbloc : rloc;
        int ry = clampi(rl[(s * NREC + r) * 2 + 0], 0, NYX - 1) + PAD;
        int rx = clampi(rl[(s * NREC + r) * 2 + 1], 0, NYX - 1) + PAD;
        float val = g_w[cur][2 * (s * NP2 + ry * NP + rx) + (isbg ? 0 : 1)];
        int base = isbg ? (2 * SNP2) : (2 * SNP2 + NS * NREC * NT);
        out_st(out, base + (s * NREC + r) * NT + (t - 1), val);
    }

    const bool active = i < 222;
    const int x0 = 2 * i, x1 = x0 + 1;
    const int yx  = y * NP + x0;
    const int idx = s * NP2 + yx;

    float4 w4 = make_float4(0.f, 0.f, 0.f, 0.f);   // (b0,s0,b1,s1)
    if (active) {
        w4 = *(const float4*)(g_w[cur] + 2 * idx);
        *(float4*)&sw[2 * x0 + 4] = w4;
    } else if (i == 222) {
        #pragma unroll
        for (int k = 0; k < 4; ++k) { sw[k] = 0.f; spx[k] = 0.f; }
    } else if (i == 223) {
        #pragma unroll
        for (int k = 892; k < 904; ++k) { sw[k] = 0.f; spx[k] = 0.f; }
    }
    __syncthreads();

    // ---- x stencils from LDS + own psi_x updates ----
    const bool pxreg = (i <= 11 || i >= 210);
    float pbx0 = 0.f, pbx1 = 0.f, pax0 = 0.f, pax1 = 0.f;
    float d2x_b0 = 0.f, d2x_b1 = 0.f, d2x_s0 = 0.f, d2x_s1 = 0.f;
    float4 pxn = make_float4(0.f, 0.f, 0.f, 0.f);
    float2 tm2, tm1, tp2, tp3;
    if (active) {
        tm2 = *(const float2*)&sw[2 * (x0 - 2) + 4];
        tm1 = *(const float2*)&sw[2 * (x0 - 1) + 4];
        tp2 = *(const float2*)&sw[2 * (x0 + 2) + 4];
        tp3 = *(const float2*)&sw[2 * (x0 + 3) + 4];
        d2x_b0 = (C2A * (tm2.x + tp2.x) + C2B * (tm1.x + w4.z) + C2C * w4.x) * INVH2;
        d2x_s0 = (C2A * (tm2.y + tp2.y) + C2B * (tm1.y + w4.w) + C2C * w4.y) * INVH2;
        d2x_b1 = (C2A * (tm1.x + tp3.x) + C2B * (w4.x + tp2.x) + C2C * w4.z) * INVH2;
        d2x_s1 = (C2A * (tm1.y + tp3.y) + C2B * (w4.y + tp2.y) + C2C * w4.w) * INVH2;
        pbx0 = g_pb[x0]; pbx1 = g_pb[x1];
        pax0 = g_pa[x0]; pax1 = g_pa[x1];
        if (pxreg && pbx0 != 0.f) {      // pb pair-uniform (frame edges even)
            float4 pxo = *(const float4*)(g_px[cur] + 2 * idx);
            float dwb0 = (C1A * tm2.x - C1B * tm1.x + C1B * w4.z - C1A * tp2.x) * INVH;
            float dws0 = (C1A * tm2.y - C1B * tm1.y + C1B * w4.w - C1A * tp2.y) * INVH;
            float dwb1 = (C1A * tm1.x - C1B * w4.x + C1B * tp2.x - C1A * tp3.x) * INVH;
            float dws1 = (C1A * tm1.y - C1B * w4.y + C1B * tp2.y - C1A * tp3.y) * INVH;
            pxn.x = pax0 * pxo.x + pbx0 * dwb0;
            pxn.y = pax0 * pxo.y + pbx0 * dws0;
            pxn.z = pax1 * pxo.z + pbx1 * dwb1;
            pxn.w = pax1 * pxo.w + pbx1 * dws1;
            *(float4*)(g_px[nxt] + 2 * idx) = pxn;
        }
        *(float4*)&spx[2 * x0 + 4] = pxn;
    }
    __syncthreads();
    if (!active) return;

    // ---- dpsi_x from LDS psi_x_new ----
    float dpx_b0 = 0.f, dpx_b1 = 0.f, dpx_s0 = 0.f, dpx_s1 = 0.f;
    if (pxreg) {
        float2 pm2 = *(const float2*)&spx[2 * (x0 - 2) + 4];
        float2 pm1 = *(const float2*)&spx[2 * (x0 - 1) + 4];
        float2 pp2 = *(const float2*)&spx[2 * (x0 + 2) + 4];
        float2 pp3 = *(const float2*)&spx[2 * (x0 + 3) + 4];
        dpx_b0 = (C1A * pm2.x - C1B * pm1.x + C1B * pxn.z - C1A * pp2.x) * INVH;
        dpx_s0 = (C1A * pm2.y - C1B * pm1.y + C1B * pxn.w - C1A * pp2.y) * INVH;
        dpx_b1 = (C1A * pm1.x - C1B * pxn.x + C1B * pp2.x - C1A * pp3.x) * INVH;
        dpx_s1 = (C1A * pm1.y - C1B * pxn.y + C1B * pp2.y - C1A * pp3.y) * INVH;
    }

    // ---- y direction ----
    const float pby = g_pb[y];               // block-uniform
    const bool yframe = (y <= 23 || y >= 420);
    float d2y_b0, d2y_b1, d2y_s0, d2y_s1;
    float dpy_b0 = 0.f, dpy_b1 = 0.f, dpy_s0 = 0.f, dpy_s1 = 0.f;
    if (yframe) {
        float4 wy[9];                        // rows y-4..y+4, (b0,s0,b1,s1)
        #pragma unroll
        for (int k = 0; k < 9; ++k)
            wy[k] = (k == 4) ? w4 : ld4(g_w[cur], s, y - 4 + k, i);
        d2y_b0 = (C2A * (wy[2].x + wy[6].x) + C2B * (wy[3].x + wy[5].x) + C2C * wy[4].x) * INVH2;
        d2y_s0 = (C2A * (wy[2].y + wy[6].y) + C2B * (wy[3].y + wy[5].y) + C2C * wy[4].y) * INVH2;
        d2y_b1 = (C2A * (wy[2].z + wy[6].z) + C2B * (wy[3].z + wy[5].z) + C2C * wy[4].z) * INVH2;
        d2y_s1 = (C2A * (wy[2].w + wy[6].w) + C2B * (wy[3].w + wy[5].w) + C2C * wy[4].w) * INVH2;
        float4 pn[5];                        // psi_y_new rows y-2..y+2
        #pragma unroll
        for (int k = 0; k < 5; ++k) {
            int yy = y - 2 + k;
            float pbv = ((unsigned)yy < (unsigned)NP) ? g_pb[yy] : 0.f;  // uniform
            float4 r = make_float4(0.f, 0.f, 0.f, 0.f);
            if (pbv != 0.f) {
                float pav = g_pa[yy];
                float4 po = *(const float4*)(g_py[cur] + 2 * (s * NP2 + yy * NP + x0));
                float db0 = (C1A * wy[k].x - C1B * wy[k+1].x + C1B * wy[k+3].x - C1A * wy[k+4].x) * INVH;
                float ds0 = (C1A * wy[k].y - C1B * wy[k+1].y + C1B * wy[k+3].y - C1A * wy[k+4].y) * INVH;
                float db1 = (C1A * wy[k].z - C1B * wy[k+1].z + C1B * wy[k+3].z - C1A * wy[k+4].z) * INVH;
                float ds1 = (C1A * wy[k].w - C1B * wy[k+1].w + C1B * wy[k+3].w - C1A * wy[k+4].w) * INVH;
                r.x = pav * po.x + pbv * db0;  r.y = pav * po.y + pbv * ds0;
                r.z = pav * po.z + pbv * db1;  r.w = pav * po.w + pbv * ds1;
            }
            pn[k] = r;
        }
        dpy_b0 = (C1A * pn[0].x - C1B * pn[1].x + C1B * pn[3].x - C1A * pn[4].x) * INVH;
        dpy_s0 = (C1A * pn[0].y - C1B * pn[1].y + C1B * pn[3].y - C1A * pn[4].y) * INVH;
        dpy_b1 = (C1A * pn[0].z - C1B * pn[1].z + C1B * pn[3].z - C1A * pn[4].z) * INVH;
        dpy_s1 = (C1A * pn[0].w - C1B * pn[1].w + C1B * pn[3].w - C1A * pn[4].w) * INVH;
        if (pby != 0.f)
            *(float4*)(g_py[nxt] + 2 * idx) = pn[2];
    } else {                                 // interior: 4 float4 row loads
        float4 m2 = *(const float4*)(g_w[cur] + 2 * (idx - 2 * NP));
        float4 m1 = *(const float4*)(g_w[cur] + 2 * (idx - NP));
        float4 p1 = *(const float4*)(g_w[cur] + 2 * (idx + NP));
        float4 p2 = *(const float4*)(g_w[cur] + 2 * (idx + 2 * NP));
        d2y_b0 = (C2A * (m2.x + p2.x) + C2B * (m1.x + p1.x) + C2C * w4.x) * INVH2;
        d2y_s0 = (C2A * (m2.y + p2.y) + C2B * (m1.y + p1.y) + C2C * w4.y) * INVH2;
        d2y_b1 = (C2A * (m2.z + p2.z) + C2B * (m1.z + p1.z) + C2C * w4.z) * INVH2;
        d2y_s1 = (C2A * (m2.w + p2.w) + C2B * (m1.w + p1.w) + C2C * w4.w) * INVH2;
    }

    // ---- zeta (in-place, own points, paired float4) ----
    float zy_b0 = 0.f, zy_b1 = 0.f, zy_s0 = 0.f, zy_s1 = 0.f;
    float zx_b0 = 0.f, zx_b1 = 0.f, zx_s0 = 0.f, zx_s1 = 0.f;
    if (pby != 0.f) {
        float pay = g_pa[y];
        float4 zo = *(const float4*)(g_zy + 2 * idx);
        zy_b0 = pay * zo.x + pby * (d2y_b0 + dpy_b0);
        zy_s0 = pay * zo.y + pby * (d2y_s0 + dpy_s0);
        zy_b1 = pay * zo.z + pby * (d2y_b1 + dpy_b1);
        zy_s1 = pay * zo.w + pby * (d2y_s1 + dpy_s1);
        *(float4*)(g_zy + 2 * idx) = make_float4(zy_b0, zy_s0, zy_b1, zy_s1);
    }
    if (pbx0 != 0.f) {                       // pair-uniform
        float4 zo = *(const float4*)(g_zx + 2 * idx);
        zx_b0 = pax0 * zo.x + pbx0 * (d2x_b0 + dpx_b0);
        zx_s0 = pax0 * zo.y + pbx0 * (d2x_s0 + dpx_s0);
        zx_b1 = pax1 * zo.z + pbx1 * (d2x_b1 + dpx_b1);
        zx_s1 = pax1 * zo.w + pbx1 * (d2x_s1 + dpx_s1);
        *(float4*)(g_zx + 2 * idx) = make_float4(zx_b0, zx_s0, zx_b1, zx_s1);
    }

    // ---- lap + leapfrog + Born + source ----
    float4 vb   = *(const float4*)(g_vb + 2 * yx);        // (v0,bs0,v1,bs1)
    float4 prev = *(const float4*)(g_w[nxt] + 2 * idx);
    float lap_b0 = d2y_b0 + d2x_b0 + dpy_b0 + dpx_b0 + zy_b0 + zx_b0;
    float lap_s0 = d2y_s0 + d2x_s0 + dpy_s0 + dpx_s0 + zy_s0 + zx_s0;
    float lap_b1 = d2y_b1 + d2x_b1 + dpy_b1 + dpx_b1 + zy_b1 + zx_b1;
    float lap_s1 = d2y_s1 + d2x_s1 + dpy_s1 + dpx_s1 + zy_s1 + zx_s1;
    float wn_b0 = vb.x * lap_b0 + 2.f * w4.x - prev.x;
    float wn_s0 = vb.x * lap_s0 + 2.f * w4.y - prev.y + vb.y * lap_b0;
    float wn_b1 = vb.z * lap_b1 + 2.f * w4.z - prev.z;
    float wn_s1 = vb.z * lap_s1 + 2.f * w4.w - prev.w + vb.w * lap_b1;
    if (y == g_spos[2 * s]) {
        int sx = g_spos[2 * s + 1];
        if (sx == x0)      { wn_b0 += g_fbg[t * NS + s]; wn_s0 += g_fsc[t * NS + s]; }
        else if (sx == x1) { wn_b1 += g_fbg[t * NS + s]; wn_s1 += g_fsc[t * NS + s]; }
    }
    *(float4*)(g_w[nxt] + 2 * idx) = make_float4(wn_b0, wn_s0, wn_b1, wn_s1);
}

__global__ void finalize(const int* __restrict__ rloc, const int* __restrict__ rbloc,
                         void* __restrict__ out) {
    int i = blockIdx.x * blockDim.x + threadIdx.x;
    const float* w0 = g_w[0];     // NT even: newest field in buffer 0
    if (i < SNP2) {
        out_st(out, i,        w0[2 * i]);       // bg flat
        out_st(out, SNP2 + i, w0[2 * i + 1]);   // scattered flat
    }
    if (i < 2 * NS * NREC) {      // record last step (t = NT-1)
        bool isbg = i < NS * NREC;
        int k = isbg ? i : i - NS * NREC;
        int s = k / NREC, r = k % NREC;
        const int* rl = isbg ? rbloc : rloc;
        int ry = clampi(rl[(s * NREC + r) * 2 + 0], 0, NYX - 1) + PAD;
        int rx = clampi(rl[(s * NREC + r) * 2 + 1], 0, NYX - 1) + PAD;
        float val = w0[2 * (s * NP2 + ry * NP + rx) + (isbg ? 0 : 1)];
        int base = isbg ? (2 * SNP2) : (2 * SNP2 + NS * NREC * NT);
        out_st(out, base + (s * NREC + r) * NT + (NT - 1), val);
    }
}

extern "C" void kernel_launch(void* const* d_in, const int* in_sizes, int n_in,
                              void* d_out, int out_size, void* d_ws, size_t ws_size,
                              hipStream_t stream) {
    const void* v   = d_in[0];
    const void* sc  = d_in[1];
    const void* amp = d_in[2];
    const int* sloc  = (const int*)d_in[3];
    const int* rloc  = (const int*)d_in[4];
    const int* rbloc = (const int*)d_in[5];

    detect_mode<<<1, 64, 0, stream>>>(v);
    zero_state<<<(SNP2 / 2 + 255) / 256, 256, 0, stream>>>();
    prep_pad<<<(NP2 + 255) / 256, 256, 0, stream>>>(v, sc);
    prep_src<<<(NT * NS + 255) / 256, 256, 0, stream>>>(amp, sloc, v, sc);

    for (int t = 0; t < NT; ++t)
        step_fused<<<NS * NP, 256, 0, stream>>>(t, rloc, rbloc, d_out);

    finalize<<<(SNP2 + 255) / 256, 256, 0, stream>>>(rloc, rbloc, d_out);
}

// Round 5
// 2317.191 us; speedup vs baseline: 1.3071x; 1.0180x over previous
//
#include <hip/hip_runtime.h>
#include <hip/hip_bf16.h>

// ScalarBorn: 4th-order FD scalar wave + Born scattering with CPML, MI355X.
// R19 = R18 (XCD-banded, bounds(256,7), 2358us) with BOTH barriers + ALL LDS
// eliminated: x-neighbor exchange via wave shuffles. Each wave owns 60
// contiguous pairs + 2-pair halo (lane l -> pair 60*w+l-2, owners l in
// [2,62)); tm/tp and psi_x_new neighborhoods come from __shfl_up/down(1).
// Rationale: __syncthreads on gfx950 emits s_waitcnt vmcnt(0) lgkmcnt(0) --
// the two barriers forced 3 serialized L2-latency drains per step (and made
// R16/R17 prefetching useless). No barriers -> waves independent, compiler
// pipelines all loads. +7% redundant halo loads is the price.
// Falsified: full hoist (R16 +19%), cheap hoist (R17 +5%), aggregation
// (R8/R10), barrier removal alone w/ LDS kept (R12/R13), load cuts (R7),
// grid.sync (R4).

constexpr int NYX  = 400;
constexpr int NS   = 4;
constexpr int NREC = 100;
constexpr int NT   = 300;
constexpr int PAD  = 22;
constexpr int NP   = 444;
constexpr int NP2  = NP * NP;          // 197136
constexpr int SNP2 = NS * NP2;         // 788544
constexpr float DT    = 0.0005f;
constexpr float INVH  = 0.2f;
constexpr float INVH2 = 0.04f;
constexpr float C1A = 1.0f / 12.0f;
constexpr float C1B = 2.0f / 3.0f;
constexpr float C2A = -1.0f / 12.0f;
constexpr float C2B = 4.0f / 3.0f;
constexpr float C2C = -2.5f;

// interleaved state: element (b,s) pair for grid index idx lives at [2*idx, 2*idx+1]
__device__ __align__(16) float g_w[2][2 * SNP2];   // wavefield ping-pong
__device__ __align__(16) float g_px[2][2 * SNP2];  // psi_x dbuf
__device__ __align__(16) float g_py[2][2 * SNP2];  // psi_y dbuf
__device__ __align__(16) float g_zx[2 * SNP2];     // zeta_x
__device__ __align__(16) float g_zy[2 * SNP2];     // zeta_y
__device__ __align__(16) float g_vb[2 * NP2];      // (v2dt2, bscale) pairs
__device__ float g_pa[NP];
__device__ float g_pb[NP];
__device__ float g_fbg[NT * NS];
__device__ float g_fsc[NT * NS];
__device__ int   g_spos[2 * NS];
__device__ int   g_mode;               // 1 = bf16 io, 0 = f32 io

__device__ __forceinline__ int clampi(int v, int lo, int hi) {
    return v < lo ? lo : (v > hi ? hi : v);
}
__device__ __forceinline__ float in_ld(const void* p, int i) {
    if (g_mode) return __bfloat162float(((const __hip_bfloat16*)p)[i]);
    return ((const float*)p)[i];
}
__device__ __forceinline__ void out_st(void* p, int i, float v) {
    if (g_mode) ((__hip_bfloat16*)p)[i] = __float2bfloat16(v);
    else        ((float*)p)[i] = v;
}
// float4 = (b0,s0,b1,s1) at row yy, col pair ip of shot s; 0 if row OOB
__device__ __forceinline__ float4 ld4(const float* w, int s, int yy, int ip) {
    if ((unsigned)yy >= (unsigned)NP) return make_float4(0.f, 0.f, 0.f, 0.f);
    return *(const float4*)(w + 2 * (s * NP2 + yy * NP + 2 * ip));
}
__device__ __forceinline__ float4 shup4(float4 v) {
    return make_float4(__shfl_up(v.x, 1), __shfl_up(v.y, 1),
                       __shfl_up(v.z, 1), __shfl_up(v.w, 1));
}
__device__ __forceinline__ float4 shdn4(float4 v) {
    return make_float4(__shfl_down(v.x, 1), __shfl_down(v.y, 1),
                       __shfl_down(v.z, 1), __shfl_down(v.w, 1));
}

__global__ void detect_mode(const void* vptr) {
    if (threadIdx.x == 0 && blockIdx.x == 0) {
        const __hip_bfloat16* p = (const __hip_bfloat16*)vptr;
        int ok = 1;
        for (int i = 0; i < 32; i += 2) {
            float f = __bfloat162float(p[i]);
            if (!(f >= 1000.f && f <= 3000.f)) ok = 0;
        }
        g_mode = ok;
    }
}

__global__ void zero_state() {
    int i = blockIdx.x * blockDim.x + threadIdx.x;
    if (i >= SNP2 / 2) return;           // each array = 2*SNP2 floats = SNP2/2 float4
    float4 z = make_float4(0.f, 0.f, 0.f, 0.f);
    ((float4*)g_w[0])[i] = z;  ((float4*)g_w[1])[i] = z;
    ((float4*)g_px[0])[i] = z; ((float4*)g_px[1])[i] = z;
    ((float4*)g_py[0])[i] = z; ((float4*)g_py[1])[i] = z;
    ((float4*)g_zx)[i] = z;    ((float4*)g_zy)[i] = z;
}

__global__ void prep_pad(const void* __restrict__ v, const void* __restrict__ sc) {
    int i = blockIdx.x * blockDim.x + threadIdx.x;
    if (i >= NP2) return;
    int y = i / NP, x = i % NP;
    int vy = clampi(y - PAD, 0, NYX - 1);
    int vx = clampi(x - PAD, 0, NYX - 1);
    float vv = in_ld(v, vy * NYX + vx);
    float vd = vv * DT;
    float s = 0.f;
    if (y >= PAD && y < PAD + NYX && x >= PAD && x < PAD + NYX)
        s = in_ld(sc, (y - PAD) * NYX + (x - PAD));
    g_vb[2 * i]     = vd * vd;
    g_vb[2 * i + 1] = 2.f * vv * s * DT * DT;
    if (i < NP) {
        float fi = (float)i;
        float f1 = fminf(fmaxf((22.f - fi) * 0.05f, 0.f), 1.f);
        float f2 = fminf(fmaxf((fi - 421.f) * 0.05f, 0.f), 1.f);
        float frac = fmaxf(f1, f2);
        float sigma = 259.0408229f * frac * frac;
        const float alpha = 78.53981634f;
        float a = expf(-(sigma + alpha) * DT);
        g_pa[i] = a;
        g_pb[i] = (sigma > 0.f) ? sigma / (sigma + alpha) * (a - 1.f) : 0.f;
    }
}

__global__ void prep_src(const void* __restrict__ amp, const int* __restrict__ sloc,
                         const void* __restrict__ v, const void* __restrict__ sc) {
    int i = blockIdx.x * blockDim.x + threadIdx.x;
    if (i >= NT * NS) return;
    int s = i % NS, t = i / NS;
    int ly = clampi(sloc[s * 2 + 0], 0, NYX - 1);
    int lx = clampi(sloc[s * 2 + 1], 0, NYX - 1);
    float a  = in_ld(amp, s * NT + t);
    float vv = in_ld(v,  ly * NYX + lx);
    float ss = in_ld(sc, ly * NYX + lx);
    g_fbg[i] = -a * vv * vv * DT * DT;
    g_fsc[i] = -2.f * a * vv * ss * DT * DT;
    if (i < NS) {
        g_spos[2 * i]     = ly + PAD;
        g_spos[2 * i + 1] = lx + PAD;
    }
}

// one fused timestep. Block = row y of shot s. Barrier-free, LDS-free:
// wave w's lane l handles pair ip = 60*w + l - 2; owners are lanes [2,62).
// x-neighbor pairs come from __shfl_up/down(1); halo lanes feed owners only.
// 1-D grid of NS*NP=1776 blocks, XCD-banded (bid%8 = XCD owns 222 consecutive
// rows of one shot -> y-stencil in local L2). bounds(256,7) -> one round.
__global__ void __launch_bounds__(256, 7)
step_fused(int t, const int* __restrict__ rloc, const int* __restrict__ rbloc,
           void* __restrict__ out) {
    const int i = threadIdx.x;
    const int bid = blockIdx.x;
    const int s = (bid >> 1) & 3;                      // xcd = bid & 7; s = xcd>>1
    const int y = ((bid & 1) ? 222 : 0) + (bid >> 3);  // band-local row
    const int cur = t & 1, nxt = cur ^ 1;

    if (t > 0 && y == 0 && i < 2 * NREC) {    // record step t-1
        int r = i % NREC;
        bool isbg = i < NREC;
        const int* rl = isbg ? rbloc : rloc;
        int ry = clampi(rl[(s * NREC + r) * 2 + 0], 0, NYX - 1) + PAD;
        int rx = clampi(rl[(s * NREC + r) * 2 + 1], 0, NYX - 1) + PAD;
        float val = g_w[cur][2 * (s * NP2 + ry * NP + rx) + (isbg ? 0 : 1)];
        int base = isbg ? (2 * SNP2) : (2 * SNP2 + NS * NREC * NT);
        out_st(out, base + (s * NREC + r) * NT + (t - 1), val);
    }

    const int wid  = i >> 6;
    const int lane = i & 63;
    const int ip   = 60 * wid + lane - 2;              // pair index
    const bool inb   = (unsigned)ip < 222u;
    const bool owner = (lane >= 2) && (lane < 62) && inb;

    const int x0 = 2 * ip, x1 = x0 + 1;
    const int yx  = y * NP + x0;
    const int idx = s * NP2 + yx;

    // ---- own pair load ----
    float4 w4 = make_float4(0.f, 0.f, 0.f, 0.f);
    if (inb) w4 = *(const float4*)(g_w[cur] + 2 * idx);

    // ---- x-neighbors via wave shuffle (pair ip-1 / ip+1) ----
    float4 wl = shup4(w4);         // pair ip-1: cols x0-2 (b,s)=wl.x/y, x0-1=wl.z/w
    float4 wr = shdn4(w4);         // pair ip+1: cols x0+2=wr.x/y, x0+3=wr.z/w

    const bool pxreg = (ip <= 11 || ip >= 210);
    float pbx0 = 0.f, pbx1 = 0.f, pax0 = 0.f, pax1 = 0.f;
    float d2x_b0 = 0.f, d2x_b1 = 0.f, d2x_s0 = 0.f, d2x_s1 = 0.f;
    float4 pxn = make_float4(0.f, 0.f, 0.f, 0.f);
    if (inb) {
        d2x_b0 = (C2A * (wl.x + wr.x) + C2B * (wl.z + w4.z) + C2C * w4.x) * INVH2;
        d2x_s0 = (C2A * (wl.y + wr.y) + C2B * (wl.w + w4.w) + C2C * w4.y) * INVH2;
        d2x_b1 = (C2A * (wl.z + wr.z) + C2B * (w4.x + wr.x) + C2C * w4.z) * INVH2;
        d2x_s1 = (C2A * (wl.w + wr.w) + C2B * (w4.y + wr.y) + C2C * w4.w) * INVH2;
        pbx0 = g_pb[x0]; pbx1 = g_pb[x1];
        pax0 = g_pa[x0]; pax1 = g_pa[x1];
        if (pxreg && pbx0 != 0.f) {      // pb pair-uniform (frame edges even)
            float4 pxo = *(const float4*)(g_px[cur] + 2 * idx);
            float dwb0 = (C1A * wl.x - C1B * wl.z + C1B * w4.z - C1A * wr.x) * INVH;
            float dws0 = (C1A * wl.y - C1B * wl.w + C1B * w4.w - C1A * wr.y) * INVH;
            float dwb1 = (C1A * wl.z - C1B * w4.x + C1B * wr.x - C1A * wr.z) * INVH;
            float dws1 = (C1A * wl.w - C1B * w4.y + C1B * wr.y - C1A * wr.w) * INVH;
            pxn.x = pax0 * pxo.x + pbx0 * dwb0;
            pxn.y = pax0 * pxo.y + pbx0 * dws0;
            pxn.z = pax1 * pxo.z + pbx1 * dwb1;
            pxn.w = pax1 * pxo.w + pbx1 * dws1;
            if (owner)
                *(float4*)(g_px[nxt] + 2 * idx) = pxn;
        }
    }

    // ---- dpsi_x via shuffle of psi_x_new ----
    float dpx_b0 = 0.f, dpx_b1 = 0.f, dpx_s0 = 0.f, dpx_s1 = 0.f;
    {
        float4 pl = shup4(pxn);    // pair ip-1 psi_x_new
        float4 pr = shdn4(pxn);    // pair ip+1 psi_x_new
        if (pxreg) {
            dpx_b0 = (C1A * pl.x - C1B * pl.z + C1B * pxn.z - C1A * pr.x) * INVH;
            dpx_s0 = (C1A * pl.y - C1B * pl.w + C1B * pxn.w - C1A * pr.y) * INVH;
            dpx_b1 = (C1A * pl.z - C1B * pxn.x + C1B * pr.x - C1A * pr.z) * INVH;
            dpx_s1 = (C1A * pl.w - C1B * pxn.y + C1B * pr.y - C1A * pr.w) * INVH;
        }
    }

    if (!owner) return;            // halo lanes done (no barrier constraints)

    // ---- y direction ----
    const float pby = g_pb[y];               // block-uniform
    const bool yframe = (y <= 23 || y >= 420);
    float d2y_b0, d2y_b1, d2y_s0, d2y_s1;
    float dpy_b0 = 0.f, dpy_b1 = 0.f, dpy_s0 = 0.f, dpy_s1 = 0.f;
    if (yframe) {
        float4 wy[9];                        // rows y-4..y+4, (b0,s0,b1,s1)
        #pragma unroll
        for (int k = 0; k < 9; ++k)
            wy[k] = (k == 4) ? w4 : ld4(g_w[cur], s, y - 4 + k, ip);
        d2y_b0 = (C2A * (wy[2].x + wy[6].x) + C2B * (wy[3].x + wy[5].x) + C2C * wy[4].x) * INVH2;
        d2y_s0 = (C2A * (wy[2].y + wy[6].y) + C2B * (wy[3].y + wy[5].y) + C2C * wy[4].y) * INVH2;
        d2y_b1 = (C2A * (wy[2].z + wy[6].z) + C2B * (wy[3].z + wy[5].z) + C2C * wy[4].z) * INVH2;
        d2y_s1 = (C2A * (wy[2].w + wy[6].w) + C2B * (wy[3].w + wy[5].w) + C2C * wy[4].w) * INVH2;
        float4 pn[5];                        // psi_y_new rows y-2..y+2
        #pragma unroll
        for (int k = 0; k < 5; ++k) {
            int yy = y - 2 + k;
            float pbv = ((unsigned)yy < (unsigned)NP) ? g_pb[yy] : 0.f;  // uniform
            float4 r = make_float4(0.f, 0.f, 0.f, 0.f);
            if (pbv != 0.f) {
                float pav = g_pa[yy];
                float4 po = *(const float4*)(g_py[cur] + 2 * (s * NP2 + yy * NP + x0));
                float db0 = (C1A * wy[k].x - C1B * wy[k+1].x + C1B * wy[k+3].x - C1A * wy[k+4].x) * INVH;
                float ds0 = (C1A * wy[k].y - C1B * wy[k+1].y + C1B * wy[k+3].y - C1A * wy[k+4].y) * INVH;
                float db1 = (C1A * wy[k].z - C1B * wy[k+1].z + C1B * wy[k+3].z - C1A * wy[k+4].z) * INVH;
                float ds1 = (C1A * wy[k].w - C1B * wy[k+1].w + C1B * wy[k+3].w - C1A * wy[k+4].w) * INVH;
                r.x = pav * po.x + pbv * db0;  r.y = pav * po.y + pbv * ds0;
                r.z = pav * po.z + pbv * db1;  r.w = pav * po.w + pbv * ds1;
            }
            pn[k] = r;
        }
        dpy_b0 = (C1A * pn[0].x - C1B * pn[1].x + C1B * pn[3].x - C1A * pn[4].x) * INVH;
        dpy_s0 = (C1A * pn[0].y - C1B * pn[1].y + C1B * pn[3].y - C1A * pn[4].y) * INVH;
        dpy_b1 = (C1A * pn[0].z - C1B * pn[1].z + C1B * pn[3].z - C1A * pn[4].z) * INVH;
        dpy_s1 = (C1A * pn[0].w - C1B * pn[1].w + C1B * pn[3].w - C1A * pn[4].w) * INVH;
        if (pby != 0.f)
            *(float4*)(g_py[nxt] + 2 * idx) = pn[2];
    } else {                                 // interior: 4 float4 row loads
        float4 m2 = *(const float4*)(g_w[cur] + 2 * (idx - 2 * NP));
        float4 m1 = *(const float4*)(g_w[cur] + 2 * (idx - NP));
        float4 p1 = *(const float4*)(g_w[cur] + 2 * (idx + NP));
        float4 p2 = *(const float4*)(g_w[cur] + 2 * (idx + 2 * NP));
        d2y_b0 = (C2A * (m2.x + p2.x) + C2B * (m1.x + p1.x) + C2C * w4.x) * INVH2;
        d2y_s0 = (C2A * (m2.y + p2.y) + C2B * (m1.y + p1.y) + C2C * w4.y) * INVH2;
        d2y_b1 = (C2A * (m2.z + p2.z) + C2B * (m1.z + p1.z) + C2C * w4.z) * INVH2;
        d2y_s1 = (C2A * (m2.w + p2.w) + C2B * (m1.w + p1.w) + C2C * w4.w) * INVH2;
    }

    // ---- zeta (in-place, own points, paired float4) ----
    float zy_b0 = 0.f, zy_b1 = 0.f, zy_s0 = 0.f, zy_s1 = 0.f;
    float zx_b0 = 0.f, zx_b1 = 0.f, zx_s0 = 0.f, zx_s1 = 0.f;
    if (pby != 0.f) {
        float pay = g_pa[y];
        float4 zo = *(const float4*)(g_zy + 2 * idx);
        zy_b0 = pay * zo.x + pby * (d2y_b0 + dpy_b0);
        zy_s0 = pay * zo.y + pby * (d2y_s0 + dpy_s0);
        zy_b1 = pay * zo.z + pby * (d2y_b1 + dpy_b1);
        zy_s1 = pay * zo.w + pby * (d2y_s1 + dpy_s1);
        *(float4*)(g_zy + 2 * idx) = make_float4(zy_b0, zy_s0, zy_b1, zy_s1);
    }
    if (pbx0 != 0.f) {                       // pair-uniform
        float4 zo = *(const float4*)(g_zx + 2 * idx);
        zx_b0 = pax0 * zo.x + pbx0 * (d2x_b0 + dpx_b0);
        zx_s0 = pax0 * zo.y + pbx0 * (d2x_s0 + dpx_s0);
        zx_b1 = pax1 * zo.z + pbx1 * (d2x_b1 + dpx_b1);
        zx_s1 = pax1 * zo.w + pbx1 * (d2x_s1 + dpx_s1);
        *(float4*)(g_zx + 2 * idx) = make_float4(zx_b0, zx_s0, zx_b1, zx_s1);
    }

    // ---- lap + leapfrog + Born + source ----
    float4 vb   = *(const float4*)(g_vb + 2 * yx);        // (v0,bs0,v1,bs1)
    float4 prev = *(const float4*)(g_w[nxt] + 2 * idx);
    float lap_b0 = d2y_b0 + d2x_b0 + dpy_b0 + dpx_b0 + zy_b0 + zx_b0;
    float lap_s0 = d2y_s0 + d2x_s0 + dpy_s0 + dpx_s0 + zy_s0 + zx_s0;
    float lap_b1 = d2y_b1 + d2x_b1 + dpy_b1 + dpx_b1 + zy_b1 + zx_b1;
    float lap_s1 = d2y_s1 + d2x_s1 + dpy_s1 + dpx_s1 + zy_s1 + zx_s1;
    float wn_b0 = vb.x * lap_b0 + 2.f * w4.x - prev.x;
    float wn_s0 = vb.x * lap_s0 + 2.f * w4.y - prev.y + vb.y * lap_b0;
    float wn_b1 = vb.z * lap_b1 + 2.f * w4.z - prev.z;
    float wn_s1 = vb.z * lap_s1 + 2.f * w4.w - prev.w + vb.w * lap_b1;
    if (y == g_spos[2 * s]) {
        int sx = g_spos[2 * s + 1];
        if (sx == x0)      { wn_b0 += g_fbg[t * NS + s]; wn_s0 += g_fsc[t * NS + s]; }
        else if (sx == x1) { wn_b1 += g_fbg[t * NS + s]; wn_s1 += g_fsc[t * NS + s]; }
    }
    *(float4*)(g_w[nxt] + 2 * idx) = make_float4(wn_b0, wn_s0, wn_b1, wn_s1);
}

__global__ void finalize(const int* __restrict__ rloc, const int* __restrict__ rbloc,
                         void* __restrict__ out) {
    int i = blockIdx.x * blockDim.x + threadIdx.x;
    const float* w0 = g_w[0];     // NT even: newest field in buffer 0
    if (i < SNP2) {
        out_st(out, i,        w0[2 * i]);       // bg flat
        out_st(out, SNP2 + i, w0[2 * i + 1]);   // scattered flat
    }
    if (i < 2 * NS * NREC) {      // record last step (t = NT-1)
        bool isbg = i < NS * NREC;
        int k = isbg ? i : i - NS * NREC;
        int s = k / NREC, r = k % NREC;
        const int* rl = isbg ? rbloc : rloc;
        int ry = clampi(rl[(s * NREC + r) * 2 + 0], 0, NYX - 1) + PAD;
        int rx = clampi(rl[(s * NREC + r) * 2 + 1], 0, NYX - 1) + PAD;
        float val = w0[2 * (s * NP2 + ry * NP + rx) + (isbg ? 0 : 1)];
        int base = isbg ? (2 * SNP2) : (2 * SNP2 + NS * NREC * NT);
        out_st(out, base + (s * NREC + r) * NT + (NT - 1), val);
    }
}

extern "C" void kernel_launch(void* const* d_in, const int* in_sizes, int n_in,
                              void* d_out, int out_size, void* d_ws, size_t ws_size,
                              hipStream_t stream) {
    const void* v   = d_in[0];
    const void* sc  = d_in[1];
    const void* amp = d_in[2];
    const int* sloc  = (const int*)d_in[3];
    const int* rloc  = (const int*)d_in[4];
    const int* rbloc = (const int*)d_in[5];

    detect_mode<<<1, 64, 0, stream>>>(v);
    zero_state<<<(SNP2 / 2 + 255) / 256, 256, 0, stream>>>();
    prep_pad<<<(NP2 + 255) / 256, 256, 0, stream>>>(v, sc);
    prep_src<<<(NT * NS + 255) / 256, 256, 0, stream>>>(amp, sloc, v, sc);

    for (int t = 0; t < NT; ++t)
        step_fused<<<NS * NP, 256, 0, stream>>>(t, rloc, rbloc, d_out);

    finalize<<<(SNP2 + 255) / 256, 256, 0, stream>>>(rloc, rbloc, d_out);
}